// Round 18
// baseline (176.738 us; speedup 1.0000x reference)
//
#include <hip/hip_runtime.h>
#include <hip/hip_bf16.h>

typedef __hip_bfloat16 bf16;
typedef float f32x4 __attribute__((ext_vector_type(4)));
typedef short s16x8 __attribute__((ext_vector_type(8)));

// ---------------------------------------------------------------------------
__device__ __forceinline__ void async_load16(const void* g, void* lds) {
  __builtin_amdgcn_global_load_lds(
      (const __attribute__((address_space(1))) void*)g,
      (__attribute__((address_space(3))) void*)lds, 16, 0, 0);
}

__device__ __forceinline__ void store_out(float* p, float v) { *p = v; }
__device__ __forceinline__ void store_out(bf16* p, float v) { *p = __float2bfloat16(v); }

// ---------------------------------------------------------------------------
// r5-proven 2-phase 128xBN GEMM body.
// BIASMODE: 0 none, 1 col-bias, 2 row-bias,
//           3 exp(scale*acc) masked col<nv + partial row-sums (stride 32),
//           4 divide by row-sum computed in-epilogue from partp (LDS-staged).
// SWZ: 1 batched (id&7), 2 chunked XCD swizzle over VGRID, 3 batched-2 (id&1).
// VAR: 0 none, 2 skip N-tiles >= ceil128(nv), 3 K-iters = ceil32(nv).
template <typename OutT, int BIASMODE, int SWZ, int BN, int VAR, int NTX, int VGRID>
__device__ __forceinline__ void gemm_body(
    const bf16* __restrict__ Ag, const bf16* __restrict__ Bg,
    OutT* Cg, const float* __restrict__ biasp, const int* __restrict__ nvalid,
    float* __restrict__ partp, float scale, int K, int lda, int ldb, int ldc,
    long long sA, long long sB, long long sC, int id, bf16* As, bf16* Bs) {
  constexpr int NFR = BN / 32;
  constexpr int BCH = BN / 64;
  constexpr int ASZ = 128 * 32;
  constexpr int BSZ = BN * 32;

  int bz = 0, tile;
  if (SWZ == 1) { bz = id & 7; tile = id >> 3; }
  else if (SWZ == 3) { bz = id & 1; tile = id >> 1; }
  else { constexpr int q = VGRID >> 3; tile = (id & 7) * q + (id >> 3); }
  const int tn = tile % NTX, tm = tile / NTX;

  int nv = 0;
  if (VAR != 0 || BIASMODE == 3 || BIASMODE == 4) nv = nvalid[bz];
  if (VAR == 2 && tn * BN >= ((nv + 127) & ~127)) return;
  const int nt = (VAR == 3) ? ((nv + 31) >> 5) : (K >> 5);

  const bf16* A = Ag + bz * sA;
  const bf16* BT = Bg + bz * sB;
  OutT* C = Cg + bz * sC;

  const int t = threadIdx.x;
  const int lane = t & 63;
  const int wid = t >> 6;
  const int wr = wid >> 1, wc = wid & 1;
  const int lo = lane & 15, hi = lane >> 4;

  const int arow0 = tm * 128, brow0 = tn * BN;

  const int idx0 = t, idx1 = 256 + t;
  const int r0 = idx0 >> 2, c0 = (idx0 & 3) * 8;
  const int r1 = idx1 >> 2, c1 = (idx1 & 3) * 8;
  const bf16* a0 = A + (long long)(arow0 + r0) * lda + c0;
  const bf16* a1 = A + (long long)(arow0 + r1) * lda + c1;
  const bf16* b0 = BT + (long long)(brow0 + r0) * ldb + c0;
  const bf16* b1 = BT + (long long)(brow0 + r1) * ldb + c1;

  f32x4 acc[4][NFR] = {};

  async_load16(a0, As + idx0 * 8);
  async_load16(a1, As + idx1 * 8);
  async_load16(b0, Bs + idx0 * 8);
  if (BCH == 2) async_load16(b1, Bs + idx1 * 8);
  __syncthreads();

  int cur = 0;
  for (int kt = 0; kt < nt; ++kt) {
    const int nxt = cur ^ 1;
    if (kt + 1 < nt) {
      const int k0 = (kt + 1) << 5;
      async_load16(a0 + k0, As + nxt * ASZ + idx0 * 8);
      async_load16(a1 + k0, As + nxt * ASZ + idx1 * 8);
      async_load16(b0 + k0, Bs + nxt * BSZ + idx0 * 8);
      if (BCH == 2) async_load16(b1 + k0, Bs + nxt * BSZ + idx1 * 8);
    }
    s16x8 a[4], b[NFR];
#pragma unroll
    for (int m = 0; m < 4; ++m)
      a[m] = *(const s16x8*)&As[cur * ASZ + (wr * 64 + m * 16 + lo) * 32 + hi * 8];
#pragma unroll
    for (int n = 0; n < NFR; ++n)
      b[n] = *(const s16x8*)&Bs[cur * BSZ + (wc * (BN / 2) + n * 16 + lo) * 32 + hi * 8];
#pragma unroll
    for (int m = 0; m < 4; ++m)
#pragma unroll
      for (int n = 0; n < NFR; ++n)
        acc[m][n] = __builtin_amdgcn_mfma_f32_16x16x32_bf16(a[m], b[n], acc[m][n], 0, 0, 0);
    __syncthreads();
    cur = nxt;
  }

  // ---- BIASMODE 4: stage this block's partial-sum rows into free LDS
  float* plds = reinterpret_cast<float*>(As);  // 16 KB = 128 rows x 32
  int nslots = 0;
  if (BIASMODE == 4) {
    nslots = (((nv + 127) & ~127) >> 7) * 2;
    const float* pg = partp + (long long)(bz * 1024 + arow0) * 32;
    for (int i = t; i < 4096; i += 256) plds[i] = pg[i];
    __syncthreads();
  }

  // ---- epilogue. C/D layout: col = lane&15, row = (lane>>4)*4 + reg
  float bcol[NFR];
#pragma unroll
  for (int n = 0; n < NFR; ++n) bcol[n] = 0.f;
  if (BIASMODE == 1) {
#pragma unroll
    for (int n = 0; n < NFR; ++n)
      bcol[n] = biasp[brow0 + wc * (BN / 2) + n * 16 + lo];
  }
#pragma unroll
  for (int m = 0; m < 4; ++m) {
    const int row = arow0 + wr * 64 + m * 16 + hi * 4;
    float br[4] = {0.f, 0.f, 0.f, 0.f};
    if (BIASMODE == 2) {
      float4 t4 = *(const float4*)&biasp[row];
      br[0] = t4.x; br[1] = t4.y; br[2] = t4.z; br[3] = t4.w;
    }
    float inv[4] = {1.f, 1.f, 1.f, 1.f};
    if (BIASMODE == 4) {
      const int lr = wr * 64 + m * 16 + hi * 4;
#pragma unroll
      for (int j = 0; j < 4; ++j) {
        float s = 0.f;
        const float* pr = plds + (lr + j) * 32;
        for (int i = 0; i < nslots; ++i) s += pr[i];
        inv[j] = 1.f / s;
      }
    }
    float rs[4] = {0.f, 0.f, 0.f, 0.f};
#pragma unroll
    for (int n = 0; n < NFR; ++n) {
      const int col = brow0 + wc * (BN / 2) + n * 16 + lo;
#pragma unroll
      for (int j = 0; j < 4; ++j) {
        float v;
        if (BIASMODE == 3)      { v = (col < nv) ? __expf(acc[m][n][j] * scale) : 0.f; rs[j] += v; }
        else if (BIASMODE == 4) v = acc[m][n][j] * inv[j];
        else                    v = acc[m][n][j] * scale + bcol[n] + br[j];
        store_out(&C[(long long)(row + j) * ldc + col], v);
      }
    }
    if (BIASMODE == 3) {
#pragma unroll
      for (int j = 0; j < 4; ++j) {
        float s = rs[j];
        s += __shfl_xor(s, 1, 64);
        s += __shfl_xor(s, 2, 64);
        s += __shfl_xor(s, 4, 64);
        s += __shfl_xor(s, 8, 64);
        if (lo == 0)
          partp[(long long)(bz * 1024 + row + j) * 32 + tn * 2 + wc] = s;
      }
    }
  }
}

// standalone wrapper
template <typename OutT, int BIASMODE, int SWZ, int BN, int VAR, int NTX, int VGRID>
__global__ void gemm_bt(const bf16* __restrict__ Ag, const bf16* __restrict__ Bg,
                        OutT* Cg, const float* __restrict__ biasp,
                        const int* __restrict__ nvalid, float* __restrict__ partp,
                        float scale, int K, int lda, int ldb, int ldc,
                        long long sA, long long sB, long long sC) {
  __shared__ bf16 As[2 * 128 * 32];
  __shared__ bf16 Bs[2 * BN * 32];
  gemm_body<OutT, BIASMODE, SWZ, BN, VAR, NTX, VGRID>(
      Ag, Bg, Cg, biasp, nvalid, partp, scale, K, lda, ldb, ldc,
      sA, sB, sC, blockIdx.x, As, Bs);
}

// ---------------------------------------------------------------------------
// prep0 — everything that needs only INPUTS:
//  [0,8) compact; [8,72) pb3; [72,840) cvt Wq,Wk,Wv; [840,1864) Wo^T;
//  [1864,2120) b2.
__global__ __launch_bounds__(256)
void prep0(const int* __restrict__ mask, int* __restrict__ cidx,
           int* __restrict__ nvalid,
           const float* __restrict__ Wq, const float* __restrict__ Wk,
           const float* __restrict__ Wv, const float* __restrict__ Wo,
           const float* __restrict__ bq, const float* __restrict__ bv,
           bf16* __restrict__ wqb, bf16* __restrict__ wkb,
           bf16* __restrict__ wvb, bf16* __restrict__ wob_t,
           float* __restrict__ pb3, float* __restrict__ b2) {
  __shared__ float tile[32][33];
  __shared__ int cnt[256];
  __shared__ int base[256];
  const int id = blockIdx.x;
  const int t = threadIdx.x;
  if (id < 8) {
    const int b = id;
    const int* m = mask + b * 2048;
    int* ci = cidx + b * 2048;
    int mv[8], c = 0;
#pragma unroll
    for (int j = 0; j < 8; ++j) { mv[j] = m[t * 8 + j]; c += (mv[j] != 0); }
    cnt[t] = c;
    __syncthreads();
    if (t == 0) {
      int s = 0;
      for (int i = 0; i < 256; ++i) { base[i] = s; s += cnt[i]; }
      nvalid[b] = s;
    }
    __syncthreads();
    int o = base[t];
#pragma unroll
    for (int j = 0; j < 8; ++j)
      if (mv[j]) ci[o++] = t * 8 + j;
  } else if (id < 72) {
    const int lid = id - 8;
    const int hc = lid >> 2, gc = lid & 3;
    const int g = gc * 256 + t;
    float acc = 0.f;
    const int h0 = hc * 64;
    for (int i = 0; i < 64; ++i)
      acc += bv[h0 + i] * Wo[(long long)(h0 + i) * 1024 + g];
    pb3[hc * 1024 + g] = acc;
  } else if (id < 840) {
    const int lid = id - 72;
    const int z = lid >> 8;
    const float* src = (z == 0) ? Wq : (z == 1) ? Wk : Wv;
    bf16* dst = (z == 0) ? wqb : (z == 1) ? wkb : wvb;
    const int base2 = (lid & 255) * 4096 + t * 16;
#pragma unroll
    for (int j = 0; j < 2; ++j) {
      float4 v0 = reinterpret_cast<const float4*>(src)[(base2 >> 2) + j * 2];
      float4 v1 = reinterpret_cast<const float4*>(src)[(base2 >> 2) + j * 2 + 1];
      union { bf16 h[8]; s16x8 v; } o;
      o.h[0] = __float2bfloat16(v0.x); o.h[1] = __float2bfloat16(v0.y);
      o.h[2] = __float2bfloat16(v0.z); o.h[3] = __float2bfloat16(v0.w);
      o.h[4] = __float2bfloat16(v1.x); o.h[5] = __float2bfloat16(v1.y);
      o.h[6] = __float2bfloat16(v1.z); o.h[7] = __float2bfloat16(v1.w);
      reinterpret_cast<s16x8*>(dst + base2)[j] = o.v;
    }
  } else if (id < 1864) {
    const int lid = id - 840;
    const int by = lid >> 5, bx = lid & 31;
    const int tx = t & 31, ty = t >> 5;
#pragma unroll
    for (int i = 0; i < 32; i += 8)
      tile[ty + i][tx] = Wo[(long long)(by * 32 + ty + i) * 1024 + bx * 32 + tx];
    __syncthreads();
#pragma unroll
    for (int i = 0; i < 32; i += 8)
      wob_t[(long long)(bx * 32 + ty + i) * 1024 + by * 32 + tx] =
          __float2bfloat16(tile[tx][ty + i]);
  } else {
    const int lid = id - 1864;
    const int w = t >> 6, lane = t & 63;
    const int d = lid * 4 + w;
    float acc = 0.f;
#pragma unroll
    for (int i = 0; i < 16; ++i) {
      const int h = lane + i * 64;
      acc += Wk[(long long)d * 1024 + h] * bq[h];
    }
    for (int off = 32; off; off >>= 1) acc += __shfl_xor(acc, off, 64);
    if (lane == 0) b2[d] = acc;
  }
}

// ---------------------------------------------------------------------------
// aux_flood — pure memory kernel (low VGPR, no big LDS):
//  [0,8192) cvt query; [8192,24576) gather-cvt kv; [24576,24580) b3 reduce.
__global__ __launch_bounds__(256)
void aux_flood(const float* __restrict__ query, bf16* __restrict__ qb,
               const float* __restrict__ kv, const int* __restrict__ cidx,
               const int* __restrict__ nvalid, bf16* __restrict__ kvc,
               const float* __restrict__ bo, const float* __restrict__ pb3,
               float* __restrict__ b3) {
  const int id = blockIdx.x;
  const int t = threadIdx.x;
  if (id < 8192) {
    const long long i = (long long)id * 256 + t;
    float4 v = reinterpret_cast<const float4*>(query)[i];
    union { bf16 h[4]; unsigned long long u; } cv;
    cv.h[0] = __float2bfloat16(v.x);
    cv.h[1] = __float2bfloat16(v.y);
    cv.h[2] = __float2bfloat16(v.z);
    cv.h[3] = __float2bfloat16(v.w);
    reinterpret_cast<unsigned long long*>(qb)[i] = cv.u;
  } else if (id < 24576) {
    const int lid = id - 8192;
    const int b = lid >> 11, s = lid & 2047;
    const int nv = nvalid[b];
    if (s >= ((nv + 127) & ~127)) return;
    const int src = cidx[b * 2048 + min(s, nv - 1)];
    const float4 v = reinterpret_cast<const float4*>(
        kv + ((long long)b * 2048 + src) * 1024)[t];
    union { bf16 h[4]; unsigned long long u; } cv;
    cv.h[0] = __float2bfloat16(v.x);
    cv.h[1] = __float2bfloat16(v.y);
    cv.h[2] = __float2bfloat16(v.z);
    cv.h[3] = __float2bfloat16(v.w);
    reinterpret_cast<unsigned long long*>(
        kvc + ((long long)b * 2048 + s) * 1024)[t] = cv.u;
  } else {
    const int lid = id - 24576;
    const int g = lid * 256 + t;
    float s = bo[g];
#pragma unroll
    for (int hc = 0; hc < 16; ++hc) s += pb3[hc * 1024 + g];
    b3[g] = s;
  }
}

// ---------------------------------------------------------------------------
// G3 — G GEMM + kvc transpose (independent consumers):
__global__ __launch_bounds__(256)
void G3(const bf16* __restrict__ qb, const bf16* __restrict__ M,
        bf16* __restrict__ G, const float* __restrict__ b2,
        const bf16* __restrict__ kvc, bf16* __restrict__ kvcT,
        const int* __restrict__ nvalid) {
  __shared__ bf16 As[2 * 128 * 32];
  __shared__ bf16 Bs[2 * 64 * 32];
  __shared__ bf16 ttile[32][33];
  const int id = blockIdx.x;
  if (id < 1024) {
    gemm_body<bf16, 1, 2, 64, 0, 16, 1024>(
        qb, M, G, b2, nullptr, nullptr, 1.f, 1024, 1024, 1024, 1024,
        0, 0, 0, id, As, Bs);
  } else {
    const int lid = id - 1024;
    const int bx = lid & 31, by = (lid >> 5) & 63, b = lid >> 11;
    if (by * 32 >= ((nvalid[b] + 31) & ~31)) return;
    const bf16* ip = kvc + (long long)b * 2048 * 1024;
    bf16* op = kvcT + (long long)b * 1024 * 2048;
    const int tx = threadIdx.x & 31, ty = threadIdx.x >> 5;
#pragma unroll
    for (int i = 0; i < 32; i += 8)
      ttile[ty + i][tx] = ip[(long long)(by * 32 + ty + i) * 1024 + bx * 32 + tx];
    __syncthreads();
#pragma unroll
    for (int i = 0; i < 32; i += 8)
      op[(long long)(bx * 32 + ty + i) * 2048 + by * 32 + tx] = ttile[tx][ty + i];
  }
}

// ---------------------------------------------------------------------------
extern "C" void kernel_launch(void* const* d_in, const int* in_sizes, int n_in,
                              void* d_out, int out_size, void* d_ws, size_t ws_size,
                              hipStream_t stream) {
  const float* query = (const float*)d_in[0];      // [8,1024,1024]
  const float* key_value = (const float*)d_in[1];  // [8,2048,1024]
  const int* key_mask = (const int*)d_in[2];       // [8,2048]
  const float* Wq = (const float*)d_in[3];
  const float* bq = (const float*)d_in[4];
  const float* Wk = (const float*)d_in[5];
  const float* bk = (const float*)d_in[6];  // cancels in softmax (row-const)
  const float* Wv = (const float*)d_in[7];
  const float* bv = (const float*)d_in[8];
  const float* Wo = (const float*)d_in[9];
  const float* bo = (const float*)d_in[10];
  float* out = (float*)d_out;
  (void)bk;

  char* ws = (char*)d_ws;
  size_t off = 0;
  auto alloc = [&](size_t bytes) {
    char* p = ws + off;
    off += (bytes + 255) & ~(size_t)255;
    return p;
  };
  bf16* qb    = (bf16*)alloc(8192ull * 1024 * 2);   // query bf16; later CV
  bf16* kvc   = (bf16*)alloc(16384ull * 1024 * 2);  // compacted kv bf16
  bf16* kvcT  = (bf16*)alloc(8192ull * 2048 * 2);   // kvc transposed [d][s']
  bf16* wkb   = (bf16*)alloc(1024ull * 1024 * 2);   // | contiguous pair (A)
  bf16* wob_t = (bf16*)alloc(1024ull * 1024 * 2);   // |
  bf16* wqb   = (bf16*)alloc(1024ull * 1024 * 2);   // | contiguous pair (BT)
  bf16* wvb   = (bf16*)alloc(1024ull * 1024 * 2);   // |
  bf16* M     = (bf16*)alloc(1024ull * 1024 * 2);   // | contiguous pair (C)
  bf16* W3T   = (bf16*)alloc(1024ull * 1024 * 2);   // |
  bf16* G     = (bf16*)alloc(8192ull * 1024 * 2);   // query@M^T + b2
  bf16* P     = (bf16*)alloc(8ull * 1024 * 2048 * 2);
  int*  cidx  = (int*)alloc(8 * 2048 * 4);
  int*  nval  = (int*)alloc(8 * 4);
  float* part = (float*)alloc(8192ull * 32 * 4);
  float* pb3  = (float*)alloc(16 * 1024 * 4);
  float* b2   = (float*)alloc(1024 * 4);
  float* b3   = (float*)alloc(1024 * 4);
  bf16* CV = qb;  // alias: qb dead after G-GEMM

  // 1. input-only prep: compact, pb3, weight cvt/transpose, b2
  prep0<<<2120, 256, 0, stream>>>(key_mask, cidx, nval, Wq, Wk, Wv, Wo,
                                  bq, bv, wqb, wkb, wvb, wob_t, pb3, b2);

  // 2. wprep GEMM (batched-2, BN=64 -> 256 blocks = 1/CU):
  //    M = wkb@wqb^T, W3T = wob_t@wvb^T
  gemm_bt<bf16, 0, 3, 64, 0, 16, 256><<<256, 256, 0, stream>>>(
      wkb, wqb, M, nullptr, nullptr, nullptr, 1.f, 1024, 1024, 1024, 1024,
      1024ll * 1024, 1024ll * 1024, 1024ll * 1024);

  // 3. memory flood: query cvt + kv gather + b3 reduce (lean codegen)
  aux_flood<<<24580, 256, 0, stream>>>(query, qb, key_value, cidx, nval, kvc,
                                       bo, pb3, b3);

  // 4. G GEMM + kvc transpose
  G3<<<17408, 256, 0, stream>>>(qb, M, G, b2, kvc, kvcT, nval);

  // 5. scores: P~ = exp((G @ kvc^T)/32) (0 beyond nv) + partial row sums
  gemm_bt<bf16, 3, 1, 128, 2, 16, 1024><<<1024, 256, 0, stream>>>(
      G, kvc, P, nullptr, nval, part, 0.03125f, 1024, 1024, 1024, 2048,
      1024ll * 1024, 2048ll * 1024, 1024ll * 2048);

  // 6. CV = (P~ @ kvc) / rowsum   (var-K, BT = kvcT)
  gemm_bt<bf16, 4, 1, 64, 3, 16, 1024><<<1024, 256, 0, stream>>>(
      P, kvcT, CV, nullptr, nval, part, 1.f, 2048, 2048, 2048, 1024,
      1024ll * 2048, 1024ll * 2048, 1024ll * 1024);

  // 7. out = CV @ W3T^T + b3  (folds Wv and Wo projections)
  gemm_bt<float, 1, 2, 64, 0, 16, 1024><<<1024, 256, 0, stream>>>(
      CV, W3T, out, b3, nullptr, nullptr, 1.f, 1024, 1024, 1024, 1024, 0, 0, 0);
}

// Round 19
// 170.086 us; speedup vs baseline: 1.0391x; 1.0391x over previous
//
#include <hip/hip_runtime.h>
#include <hip/hip_bf16.h>

typedef __hip_bfloat16 bf16;
typedef float f32x4 __attribute__((ext_vector_type(4)));
typedef short s16x8 __attribute__((ext_vector_type(8)));

// ---------------------------------------------------------------------------
__device__ __forceinline__ void async_load16(const void* g, void* lds) {
  __builtin_amdgcn_global_load_lds(
      (const __attribute__((address_space(1))) void*)g,
      (__attribute__((address_space(3))) void*)lds, 16, 0, 0);
}

__device__ __forceinline__ void store_out(float* p, float v) { *p = v; }
__device__ __forceinline__ void store_out(bf16* p, float v) { *p = __float2bfloat16(v); }

// ---------------------------------------------------------------------------
// r5-proven 2-phase 128xBN GEMM body.
// BIASMODE: 0 none, 1 col-bias, 2 row-bias,
//           3 exp(scale*acc) masked col<nv + partial row-sums (stride 32),
//           4 divide by row-sum computed in-epilogue from partp (LDS-staged).
// SWZ: 1 batched (id&7), 2 chunked XCD swizzle over VGRID, 3 batched-2 (id&1).
// VAR: 0 none, 2 skip N-tiles >= ceil128(nv), 3 K-iters = ceil32(nv).
template <typename OutT, int BIASMODE, int SWZ, int BN, int VAR, int NTX, int VGRID>
__device__ __forceinline__ void gemm_body(
    const bf16* __restrict__ Ag, const bf16* __restrict__ Bg,
    OutT* Cg, const float* __restrict__ biasp, const int* __restrict__ nvalid,
    float* __restrict__ partp, float scale, int K, int lda, int ldb, int ldc,
    long long sA, long long sB, long long sC, int id, bf16* As, bf16* Bs) {
  constexpr int NFR = BN / 32;
  constexpr int BCH = BN / 64;
  constexpr int ASZ = 128 * 32;
  constexpr int BSZ = BN * 32;

  int bz = 0, tile;
  if (SWZ == 1) { bz = id & 7; tile = id >> 3; }
  else if (SWZ == 3) { bz = id & 1; tile = id >> 1; }
  else { constexpr int q = VGRID >> 3; tile = (id & 7) * q + (id >> 3); }
  const int tn = tile % NTX, tm = tile / NTX;

  int nv = 0;
  if (VAR != 0 || BIASMODE == 3 || BIASMODE == 4) nv = nvalid[bz];
  if (VAR == 2 && tn * BN >= ((nv + 127) & ~127)) return;
  const int nt = (VAR == 3) ? ((nv + 31) >> 5) : (K >> 5);

  const bf16* A = Ag + bz * sA;
  const bf16* BT = Bg + bz * sB;
  OutT* C = Cg + bz * sC;

  const int t = threadIdx.x;
  const int lane = t & 63;
  const int wid = t >> 6;
  const int wr = wid >> 1, wc = wid & 1;
  const int lo = lane & 15, hi = lane >> 4;

  const int arow0 = tm * 128, brow0 = tn * BN;

  const int idx0 = t, idx1 = 256 + t;
  const int r0 = idx0 >> 2, c0 = (idx0 & 3) * 8;
  const int r1 = idx1 >> 2, c1 = (idx1 & 3) * 8;
  const bf16* a0 = A + (long long)(arow0 + r0) * lda + c0;
  const bf16* a1 = A + (long long)(arow0 + r1) * lda + c1;
  const bf16* b0 = BT + (long long)(brow0 + r0) * ldb + c0;
  const bf16* b1 = BT + (long long)(brow0 + r1) * ldb + c1;

  f32x4 acc[4][NFR] = {};

  async_load16(a0, As + idx0 * 8);
  async_load16(a1, As + idx1 * 8);
  async_load16(b0, Bs + idx0 * 8);
  if (BCH == 2) async_load16(b1, Bs + idx1 * 8);
  __syncthreads();

  int cur = 0;
  for (int kt = 0; kt < nt; ++kt) {
    const int nxt = cur ^ 1;
    if (kt + 1 < nt) {
      const int k0 = (kt + 1) << 5;
      async_load16(a0 + k0, As + nxt * ASZ + idx0 * 8);
      async_load16(a1 + k0, As + nxt * ASZ + idx1 * 8);
      async_load16(b0 + k0, Bs + nxt * BSZ + idx0 * 8);
      if (BCH == 2) async_load16(b1 + k0, Bs + nxt * BSZ + idx1 * 8);
    }
    s16x8 a[4], b[NFR];
#pragma unroll
    for (int m = 0; m < 4; ++m)
      a[m] = *(const s16x8*)&As[cur * ASZ + (wr * 64 + m * 16 + lo) * 32 + hi * 8];
#pragma unroll
    for (int n = 0; n < NFR; ++n)
      b[n] = *(const s16x8*)&Bs[cur * BSZ + (wc * (BN / 2) + n * 16 + lo) * 32 + hi * 8];
#pragma unroll
    for (int m = 0; m < 4; ++m)
#pragma unroll
      for (int n = 0; n < NFR; ++n)
        acc[m][n] = __builtin_amdgcn_mfma_f32_16x16x32_bf16(a[m], b[n], acc[m][n], 0, 0, 0);
    __syncthreads();
    cur = nxt;
  }

  // ---- BIASMODE 4: stage this block's partial-sum rows into free LDS
  float* plds = reinterpret_cast<float*>(As);  // 16 KB = 128 rows x 32
  int nslots = 0;
  if (BIASMODE == 4) {
    nslots = (((nv + 127) & ~127) >> 7) * 2;
    const float* pg = partp + (long long)(bz * 1024 + arow0) * 32;
    for (int i = t; i < 4096; i += 256) plds[i] = pg[i];
    __syncthreads();
  }

  // ---- epilogue. C/D layout: col = lane&15, row = (lane>>4)*4 + reg
  float bcol[NFR];
#pragma unroll
  for (int n = 0; n < NFR; ++n) bcol[n] = 0.f;
  if (BIASMODE == 1) {
#pragma unroll
    for (int n = 0; n < NFR; ++n)
      bcol[n] = biasp[brow0 + wc * (BN / 2) + n * 16 + lo];
  }
#pragma unroll
  for (int m = 0; m < 4; ++m) {
    const int row = arow0 + wr * 64 + m * 16 + hi * 4;
    float br[4] = {0.f, 0.f, 0.f, 0.f};
    if (BIASMODE == 2) {
      float4 t4 = *(const float4*)&biasp[row];
      br[0] = t4.x; br[1] = t4.y; br[2] = t4.z; br[3] = t4.w;
    }
    float inv[4] = {1.f, 1.f, 1.f, 1.f};
    if (BIASMODE == 4) {
      const int lr = wr * 64 + m * 16 + hi * 4;
#pragma unroll
      for (int j = 0; j < 4; ++j) {
        float s = 0.f;
        const float* pr = plds + (lr + j) * 32;
        for (int i = 0; i < nslots; ++i) s += pr[i];
        inv[j] = 1.f / s;
      }
    }
    float rs[4] = {0.f, 0.f, 0.f, 0.f};
#pragma unroll
    for (int n = 0; n < NFR; ++n) {
      const int col = brow0 + wc * (BN / 2) + n * 16 + lo;
#pragma unroll
      for (int j = 0; j < 4; ++j) {
        float v;
        if (BIASMODE == 3)      { v = (col < nv) ? __expf(acc[m][n][j] * scale) : 0.f; rs[j] += v; }
        else if (BIASMODE == 4) v = acc[m][n][j] * inv[j];
        else                    v = acc[m][n][j] * scale + bcol[n] + br[j];
        store_out(&C[(long long)(row + j) * ldc + col], v);
      }
    }
    if (BIASMODE == 3) {
#pragma unroll
      for (int j = 0; j < 4; ++j) {
        float s = rs[j];
        s += __shfl_xor(s, 1, 64);
        s += __shfl_xor(s, 2, 64);
        s += __shfl_xor(s, 4, 64);
        s += __shfl_xor(s, 8, 64);
        if (lo == 0)
          partp[(long long)(bz * 1024 + row + j) * 32 + tn * 2 + wc] = s;
      }
    }
  }
}

// standalone wrapper
template <typename OutT, int BIASMODE, int SWZ, int BN, int VAR, int NTX, int VGRID>
__global__ void gemm_bt(const bf16* __restrict__ Ag, const bf16* __restrict__ Bg,
                        OutT* Cg, const float* __restrict__ biasp,
                        const int* __restrict__ nvalid, float* __restrict__ partp,
                        float scale, int K, int lda, int ldb, int ldc,
                        long long sA, long long sB, long long sC) {
  __shared__ bf16 As[2 * 128 * 32];
  __shared__ bf16 Bs[2 * BN * 32];
  gemm_body<OutT, BIASMODE, SWZ, BN, VAR, NTX, VGRID>(
      Ag, Bg, Cg, biasp, nvalid, partp, scale, K, lda, ldb, ldc,
      sA, sB, sC, blockIdx.x, As, Bs);
}

// ---------------------------------------------------------------------------
// prep0 — everything that needs only INPUTS:
//  [0,8) compact; [8,72) pb3; [72,840) cvt Wq,Wk,Wv; [840,1864) Wo^T;
//  [1864,2120) b2.
__global__ __launch_bounds__(256)
void prep0(const int* __restrict__ mask, int* __restrict__ cidx,
           int* __restrict__ nvalid,
           const float* __restrict__ Wq, const float* __restrict__ Wk,
           const float* __restrict__ Wv, const float* __restrict__ Wo,
           const float* __restrict__ bq, const float* __restrict__ bv,
           bf16* __restrict__ wqb, bf16* __restrict__ wkb,
           bf16* __restrict__ wvb, bf16* __restrict__ wob_t,
           float* __restrict__ pb3, float* __restrict__ b2) {
  __shared__ float tile[32][33];
  __shared__ int cnt[256];
  __shared__ int base[256];
  const int id = blockIdx.x;
  const int t = threadIdx.x;
  if (id < 8) {
    const int b = id;
    const int* m = mask + b * 2048;
    int* ci = cidx + b * 2048;
    int mv[8], c = 0;
#pragma unroll
    for (int j = 0; j < 8; ++j) { mv[j] = m[t * 8 + j]; c += (mv[j] != 0); }
    cnt[t] = c;
    __syncthreads();
    if (t == 0) {
      int s = 0;
      for (int i = 0; i < 256; ++i) { base[i] = s; s += cnt[i]; }
      nvalid[b] = s;
    }
    __syncthreads();
    int o = base[t];
#pragma unroll
    for (int j = 0; j < 8; ++j)
      if (mv[j]) ci[o++] = t * 8 + j;
  } else if (id < 72) {
    const int lid = id - 8;
    const int hc = lid >> 2, gc = lid & 3;
    const int g = gc * 256 + t;
    float acc = 0.f;
    const int h0 = hc * 64;
    for (int i = 0; i < 64; ++i)
      acc += bv[h0 + i] * Wo[(long long)(h0 + i) * 1024 + g];
    pb3[hc * 1024 + g] = acc;
  } else if (id < 840) {
    const int lid = id - 72;
    const int z = lid >> 8;
    const float* src = (z == 0) ? Wq : (z == 1) ? Wk : Wv;
    bf16* dst = (z == 0) ? wqb : (z == 1) ? wkb : wvb;
    const int base2 = (lid & 255) * 4096 + t * 16;
#pragma unroll
    for (int j = 0; j < 2; ++j) {
      float4 v0 = reinterpret_cast<const float4*>(src)[(base2 >> 2) + j * 2];
      float4 v1 = reinterpret_cast<const float4*>(src)[(base2 >> 2) + j * 2 + 1];
      union { bf16 h[8]; s16x8 v; } o;
      o.h[0] = __float2bfloat16(v0.x); o.h[1] = __float2bfloat16(v0.y);
      o.h[2] = __float2bfloat16(v0.z); o.h[3] = __float2bfloat16(v0.w);
      o.h[4] = __float2bfloat16(v1.x); o.h[5] = __float2bfloat16(v1.y);
      o.h[6] = __float2bfloat16(v1.z); o.h[7] = __float2bfloat16(v1.w);
      reinterpret_cast<s16x8*>(dst + base2)[j] = o.v;
    }
  } else if (id < 1864) {
    const int lid = id - 840;
    const int by = lid >> 5, bx = lid & 31;
    const int tx = t & 31, ty = t >> 5;
#pragma unroll
    for (int i = 0; i < 32; i += 8)
      tile[ty + i][tx] = Wo[(long long)(by * 32 + ty + i) * 1024 + bx * 32 + tx];
    __syncthreads();
#pragma unroll
    for (int i = 0; i < 32; i += 8)
      wob_t[(long long)(bx * 32 + ty + i) * 1024 + by * 32 + tx] =
          __float2bfloat16(tile[tx][ty + i]);
  } else {
    const int lid = id - 1864;
    const int w = t >> 6, lane = t & 63;
    const int d = lid * 4 + w;
    float acc = 0.f;
#pragma unroll
    for (int i = 0; i < 16; ++i) {
      const int h = lane + i * 64;
      acc += Wk[(long long)d * 1024 + h] * bq[h];
    }
    for (int off = 32; off; off >>= 1) acc += __shfl_xor(acc, off, 64);
    if (lane == 0) b2[d] = acc;
  }
}

// ---------------------------------------------------------------------------
// aux2 — needs prep0 outputs. Flood branches grid-strided x4 (G11):
//  [0,128)      wprep GEMM (batched-2, BN=128): M = wkb@wqb^T, W3T = wob_t@wvb^T
//  [128,2176)   cvt query: 2048 blocks x 4 float4/thread
//  [2176,6272)  gather-cvt kv: 4096 blocks x 4 rows
//  [6272,6276)  b3[g] = sum_hc pb3[hc][g] + bo[g]
__global__ __launch_bounds__(256)
void aux2(const bf16* __restrict__ wkb, const bf16* __restrict__ wqb,
          bf16* __restrict__ M,
          const float* __restrict__ query, bf16* __restrict__ qb,
          const float* __restrict__ kv, const int* __restrict__ cidx,
          const int* __restrict__ nvalid, bf16* __restrict__ kvc,
          const float* __restrict__ bo, const float* __restrict__ pb3,
          float* __restrict__ b3) {
  __shared__ bf16 As[2 * 128 * 32];
  __shared__ bf16 Bs[2 * 128 * 32];
  const int id = blockIdx.x;
  const int t = threadIdx.x;
  if (id < 128) {
    gemm_body<bf16, 0, 3, 128, 0, 8, 128>(
        wkb, wqb, M, nullptr, nullptr, nullptr, 1.f, 1024, 1024, 1024, 1024,
        1024ll * 1024, 1024ll * 1024, 1024ll * 1024, id, As, Bs);
  } else if (id < 2176) {
    const int lid = id - 128;
#pragma unroll
    for (int j = 0; j < 4; ++j) {
      const long long i = (long long)(lid * 4 + j) * 256 + t;
      float4 v = reinterpret_cast<const float4*>(query)[i];
      union { bf16 h[4]; unsigned long long u; } cv;
      cv.h[0] = __float2bfloat16(v.x);
      cv.h[1] = __float2bfloat16(v.y);
      cv.h[2] = __float2bfloat16(v.z);
      cv.h[3] = __float2bfloat16(v.w);
      reinterpret_cast<unsigned long long*>(qb)[i] = cv.u;
    }
  } else if (id < 6272) {
    const int lid = id - 2176;
    const int b = lid >> 9;              // 512 blocks/batch x 4 rows = 2048
    const int s0 = (lid & 511) * 4;
    const int nv = nvalid[b];
    const int lim = (nv + 127) & ~127;
#pragma unroll
    for (int j = 0; j < 4; ++j) {
      const int s = s0 + j;
      if (s >= lim) continue;
      const int src = cidx[b * 2048 + min(s, nv - 1)];
      const float4 v = reinterpret_cast<const float4*>(
          kv + ((long long)b * 2048 + src) * 1024)[t];
      union { bf16 h[4]; unsigned long long u; } cv;
      cv.h[0] = __float2bfloat16(v.x);
      cv.h[1] = __float2bfloat16(v.y);
      cv.h[2] = __float2bfloat16(v.z);
      cv.h[3] = __float2bfloat16(v.w);
      reinterpret_cast<unsigned long long*>(
          kvc + ((long long)b * 2048 + s) * 1024)[t] = cv.u;
    }
  } else {
    const int lid = id - 6272;
    const int g = lid * 256 + t;
    float s = bo[g];
#pragma unroll
    for (int hc = 0; hc < 16; ++hc) s += pb3[hc * 1024 + g];
    b3[g] = s;
  }
}

// ---------------------------------------------------------------------------
// G3 — G GEMM + kvc transpose (independent consumers of aux2):
__global__ __launch_bounds__(256)
void G3(const bf16* __restrict__ qb, const bf16* __restrict__ M,
        bf16* __restrict__ G, const float* __restrict__ b2,
        const bf16* __restrict__ kvc, bf16* __restrict__ kvcT,
        const int* __restrict__ nvalid) {
  __shared__ bf16 As[2 * 128 * 32];
  __shared__ bf16 Bs[2 * 64 * 32];
  __shared__ bf16 ttile[32][33];
  const int id = blockIdx.x;
  if (id < 1024) {
    gemm_body<bf16, 1, 2, 64, 0, 16, 1024>(
        qb, M, G, b2, nullptr, nullptr, 1.f, 1024, 1024, 1024, 1024,
        0, 0, 0, id, As, Bs);
  } else {
    const int lid = id - 1024;
    const int bx = lid & 31, by = (lid >> 5) & 63, b = lid >> 11;
    if (by * 32 >= ((nvalid[b] + 31) & ~31)) return;
    const bf16* ip = kvc + (long long)b * 2048 * 1024;
    bf16* op = kvcT + (long long)b * 1024 * 2048;
    const int tx = threadIdx.x & 31, ty = threadIdx.x >> 5;
#pragma unroll
    for (int i = 0; i < 32; i += 8)
      ttile[ty + i][tx] = ip[(long long)(by * 32 + ty + i) * 1024 + bx * 32 + tx];
    __syncthreads();
#pragma unroll
    for (int i = 0; i < 32; i += 8)
      op[(long long)(bx * 32 + ty + i) * 2048 + by * 32 + tx] = ttile[tx][ty + i];
  }
}

// ---------------------------------------------------------------------------
extern "C" void kernel_launch(void* const* d_in, const int* in_sizes, int n_in,
                              void* d_out, int out_size, void* d_ws, size_t ws_size,
                              hipStream_t stream) {
  const float* query = (const float*)d_in[0];      // [8,1024,1024]
  const float* key_value = (const float*)d_in[1];  // [8,2048,1024]
  const int* key_mask = (const int*)d_in[2];       // [8,2048]
  const float* Wq = (const float*)d_in[3];
  const float* bq = (const float*)d_in[4];
  const float* Wk = (const float*)d_in[5];
  const float* bk = (const float*)d_in[6];  // cancels in softmax (row-const)
  const float* Wv = (const float*)d_in[7];
  const float* bv = (const float*)d_in[8];
  const float* Wo = (const float*)d_in[9];
  const float* bo = (const float*)d_in[10];
  float* out = (float*)d_out;
  (void)bk;

  char* ws = (char*)d_ws;
  size_t off = 0;
  auto alloc = [&](size_t bytes) {
    char* p = ws + off;
    off += (bytes + 255) & ~(size_t)255;
    return p;
  };
  bf16* qb    = (bf16*)alloc(8192ull * 1024 * 2);   // query bf16; later CV
  bf16* kvc   = (bf16*)alloc(16384ull * 1024 * 2);  // compacted kv bf16
  bf16* kvcT  = (bf16*)alloc(8192ull * 2048 * 2);   // kvc transposed [d][s']
  bf16* wkb   = (bf16*)alloc(1024ull * 1024 * 2);   // | contiguous pair (A)
  bf16* wob_t = (bf16*)alloc(1024ull * 1024 * 2);   // |
  bf16* wqb   = (bf16*)alloc(1024ull * 1024 * 2);   // | contiguous pair (BT)
  bf16* wvb   = (bf16*)alloc(1024ull * 1024 * 2);   // |
  bf16* M     = (bf16*)alloc(1024ull * 1024 * 2);   // | contiguous pair (C)
  bf16* W3T   = (bf16*)alloc(1024ull * 1024 * 2);   // |
  bf16* G     = (bf16*)alloc(8192ull * 1024 * 2);   // query@M^T + b2
  bf16* P     = (bf16*)alloc(8ull * 1024 * 2048 * 2);
  int*  cidx  = (int*)alloc(8 * 2048 * 4);
  int*  nval  = (int*)alloc(8 * 4);
  float* part = (float*)alloc(8192ull * 32 * 4);
  float* pb3  = (float*)alloc(16 * 1024 * 4);
  float* b2   = (float*)alloc(1024 * 4);
  float* b3   = (float*)alloc(1024 * 4);
  bf16* CV = qb;  // alias: qb dead after G-GEMM

  // 1. input-only prep: compact, pb3, weight cvt/transpose, b2
  prep0<<<2120, 256, 0, stream>>>(key_mask, cidx, nval, Wq, Wk, Wv, Wo,
                                  bq, bv, wqb, wkb, wvb, wob_t, pb3, b2);

  // 2. wprep GEMM (hidden) + grid-strided query cvt + kv gather + b3
  aux2<<<6276, 256, 0, stream>>>(wkb, wqb, M, query, qb, key_value, cidx,
                                 nval, kvc, bo, pb3, b3);

  // 3. G GEMM + kvc transpose
  G3<<<17408, 256, 0, stream>>>(qb, M, G, b2, kvc, kvcT, nval);

  // 4. scores: P~ = exp((G @ kvc^T)/32) (0 beyond nv) + partial row sums
  gemm_bt<bf16, 3, 1, 128, 2, 16, 1024><<<1024, 256, 0, stream>>>(
      G, kvc, P, nullptr, nval, part, 0.03125f, 1024, 1024, 1024, 2048,
      1024ll * 1024, 2048ll * 1024, 1024ll * 2048);

  // 5. CV = (P~ @ kvc) / rowsum   (var-K, BT = kvcT)
  gemm_bt<bf16, 4, 1, 64, 3, 16, 1024><<<1024, 256, 0, stream>>>(
      P, kvcT, CV, nullptr, nval, part, 1.f, 2048, 2048, 2048, 1024,
      1024ll * 2048, 1024ll * 2048, 1024ll * 1024);

  // 6. out = CV @ W3T^T + b3  (folds Wv and Wo projections)
  gemm_bt<float, 1, 2, 64, 0, 16, 1024><<<1024, 256, 0, stream>>>(
      CV, W3T, out, b3, nullptr, nullptr, 1.f, 1024, 1024, 1024, 1024, 0, 0, 0);
}